// Round 2
// baseline (19130.289 us; speedup 1.0000x reference)
//
#include <hip/hip_runtime.h>
#include <hip/hip_bf16.h>

#define BB   16
#define TD   256
#define TE   1024
#define DM   512
#define DFF  2048
#define NL   6
#define NH   8
#define DH   64

typedef unsigned short u16;

__device__ __forceinline__ float b2f(u16 u) {
    unsigned int x = ((unsigned int)u) << 16;
    float f;
    __builtin_memcpy(&f, &x, 4);
    return f;
}
__device__ __forceinline__ u16 f2b(float f) {
    unsigned int x;
    __builtin_memcpy(&x, &f, 4);
    unsigned int r = x + 0x7fffu + ((x >> 16) & 1u);
    return (u16)(r >> 16);
}

// dtype sentinel: ln1_g is all-ones. f32 word 0x3F800000 (low16==0); bf16 pair 0x3F803F80.
__device__ __forceinline__ int is_bf16(const void* dt) {
    return ((*(const unsigned int*)dt) & 0xFFFFu) != 0;
}

// dual-pointer scalar load: pb valid if bf16, pf valid if f32 (element index i)
__device__ __forceinline__ float ld2(const void* pb, const void* pf, size_t i, int isbf) {
    return isbf ? b2f(((const u16*)pb)[i]) : ((const float*)pf)[i];
}
__device__ __forceinline__ void load4_2(const void* pb, const void* pf, size_t i, int isbf, float* a) {
    if (isbf) {
        ushort4 v = *reinterpret_cast<const ushort4*>((const u16*)pb + i);
        a[0] = b2f(v.x); a[1] = b2f(v.y); a[2] = b2f(v.z); a[3] = b2f(v.w);
    } else {
        float4 v = *reinterpret_cast<const float4*>((const float*)pf + i);
        a[0] = v.x; a[1] = v.y; a[2] = v.z; a[3] = v.w;
    }
}
__device__ __forceinline__ void load4f(const float* p, float* a) {
    const float4 v = *reinterpret_cast<const float4*>(p);
    a[0] = v.x; a[1] = v.y; a[2] = v.z; a[3] = v.w;
}

// ---------------- embedding + sinusoidal PE ----------------
__global__ __launch_bounds__(256) void embed_kernel(const int* __restrict__ targets,
                                                    const void* __restrict__ emb,
                                                    float* __restrict__ out,
                                                    const void* __restrict__ dt) {
    int isbf = is_bf16(dt);
    int row = blockIdx.x;
    int t   = row & (TD - 1);
    int tgt = targets[row];
    const float c = -0.017988946039015984f;   // -ln(10000)/512
    for (int d = threadIdx.x; d < DM; d += 256) {
        float e   = ld2(emb, emb, (size_t)tgt * DM + d, isbf) * 22.627416997969522f;
        int   i2  = d & ~1;
        float div = expf(c * (float)i2);
        float arg = (float)t * div;
        float pe  = (d & 1) ? cosf(arg) : sinf(arg);
        out[(size_t)row * DM + d] = e + pe;
    }
}

// ---------------- layernorm; g/b offset by `vo` elements ----------------
__global__ __launch_bounds__(256) void ln_kernel(const float* __restrict__ X,
                                                 const void* __restrict__ g,
                                                 const void* __restrict__ b,
                                                 size_t vo,
                                                 float* __restrict__ O,
                                                 const void* __restrict__ dt) {
    int isbf = is_bf16(dt);
    int row = blockIdx.x;
    const float* xr = X + (size_t)row * DM;
    int tid = threadIdx.x;
    float v0 = xr[tid], v1 = xr[tid + 256];
    float s = v0 + v1;
    __shared__ float red[4];
    int lane = tid & 63, wid = tid >> 6;
#pragma unroll
    for (int off = 32; off; off >>= 1) s += __shfl_xor(s, off);
    if (lane == 0) red[wid] = s;
    __syncthreads();
    float mean = (red[0] + red[1] + red[2] + red[3]) * (1.0f / 512.0f);
    float d0 = v0 - mean, d1 = v1 - mean;
    float sq = d0 * d0 + d1 * d1;
#pragma unroll
    for (int off = 32; off; off >>= 1) sq += __shfl_xor(sq, off);
    __syncthreads();
    if (lane == 0) red[wid] = sq;
    __syncthreads();
    float var = (red[0] + red[1] + red[2] + red[3]) * (1.0f / 512.0f);
    float rs  = rsqrtf(var + 1e-5f);
    O[(size_t)row * DM + tid]       = d0 * rs * ld2(g, g, vo + tid, isbf)       + ld2(b, b, vo + tid, isbf);
    O[(size_t)row * DM + tid + 256] = d1 * rs * ld2(g, g, vo + tid + 256, isbf) + ld2(b, b, vo + tid + 256, isbf);
}

// ---------------- GEMM: C = act(A[MxK] @ W[KxN] + bias) (+resid) ----------------
// W indexed from base with element offset `wofs`; bias with `bofs`.
template <bool AEXT, bool RELU, bool RES>
__global__ __launch_bounds__(256) void gemm_kernel(const void* __restrict__ A,
                                                   const void* __restrict__ W, size_t wofs,
                                                   const void* __restrict__ bias, size_t bofs,
                                                   const float* __restrict__ resid,
                                                   float* __restrict__ C,
                                                   int M, int N, int K,
                                                   const void* __restrict__ dt) {
    int isbf = is_bf16(dt);
    __shared__ float As[64][17];
    __shared__ float Bs[16][65];
    int tid  = threadIdx.x;
    int col0 = blockIdx.x * 64;
    int row0 = blockIdx.y * 64;
    int tx = tid & 15, ty = tid >> 4;
    float acc[4][4] = {};
    int ar = tid >> 2;
    int ak = (tid & 3) << 2;
    int wr = tid >> 4;
    int wn = (tid & 15) << 2;

    for (int k0 = 0; k0 < K; k0 += 16) {
        float av[4];
        if (AEXT) load4_2(A, A, (size_t)(row0 + ar) * K + k0 + ak, isbf, av);
        else      load4f((const float*)A + (size_t)(row0 + ar) * K + k0 + ak, av);
        As[ar][ak + 0] = av[0]; As[ar][ak + 1] = av[1];
        As[ar][ak + 2] = av[2]; As[ar][ak + 3] = av[3];
        float wv[4];
        load4_2(W, W, wofs + (size_t)(k0 + wr) * N + col0 + wn, isbf, wv);
        Bs[wr][wn + 0] = wv[0]; Bs[wr][wn + 1] = wv[1];
        Bs[wr][wn + 2] = wv[2]; Bs[wr][wn + 3] = wv[3];
        __syncthreads();
#pragma unroll
        for (int kk = 0; kk < 16; ++kk) {
            float a[4], bb[4];
#pragma unroll
            for (int i = 0; i < 4; ++i) a[i] = As[ty * 4 + i][kk];
#pragma unroll
            for (int j = 0; j < 4; ++j) bb[j] = Bs[kk][tx * 4 + j];
#pragma unroll
            for (int i = 0; i < 4; ++i)
#pragma unroll
                for (int j = 0; j < 4; ++j)
                    acc[i][j] = fmaf(a[i], bb[j], acc[i][j]);
        }
        __syncthreads();
    }
#pragma unroll
    for (int i = 0; i < 4; ++i) {
        int r = row0 + ty * 4 + i;
#pragma unroll
        for (int j = 0; j < 4; ++j) {
            int c = col0 + tx * 4 + j;
            float v = acc[i][j] + ld2(bias, bias, bofs + c, isbf);
            if (RES)  v += resid[(size_t)r * N + c];
            if (RELU) v = fmaxf(v, 0.0f);
            C[(size_t)r * N + c] = v;
        }
    }
}

// ---------------- fused attention: one wave per (b,h,tq), online softmax ----------------
__global__ __launch_bounds__(64) void attn_kernel(const float* __restrict__ Q,
                                                  const float* __restrict__ K,
                                                  const float* __restrict__ V,
                                                  const int* __restrict__ lens,
                                                  float* __restrict__ O,
                                                  int Tq, int Tk, int causal) {
    int idx  = blockIdx.x;
    int tq   = idx % Tq;
    int h    = (idx / Tq) & (NH - 1);
    int b    = idx / (Tq * NH);
    int lane = threadIdx.x;
    int kmax = lens[b];
    if (causal) kmax = min(kmax, tq + 1);
    size_t qoff = (size_t)(b * Tq + tq) * DM + h * DH;
    float qv = Q[qoff + lane] * 0.125f;
    const float* Kb = K + (size_t)b * Tk * DM + h * DH + lane;
    const float* Vb = V + (size_t)b * Tk * DM + h * DH + lane;
    float m = -1e30f, l = 0.0f, acc = 0.0f;
    for (int tk = 0; tk < kmax; ++tk) {
        float s = qv * Kb[(size_t)tk * DM];
#pragma unroll
        for (int off = 32; off; off >>= 1) s += __shfl_xor(s, off);
        float mn = fmaxf(m, s);
        float sc = __expf(m - mn);
        float p  = __expf(s - mn);
        l   = l * sc + p;
        acc = acc * sc + p * Vb[(size_t)tk * DM];
        m = mn;
    }
    O[qoff + lane] = acc / l;
}

// ---------------- f32 -> output (dtype per flag) ----------------
__global__ __launch_bounds__(256) void store_out_kernel(const float* __restrict__ X,
                                                        void* __restrict__ out, int n,
                                                        const void* __restrict__ dt) {
    int isbf = is_bf16(dt);
    int i = blockIdx.x * 256 + threadIdx.x;
    if (i < n) {
        if (isbf) ((u16*)out)[i] = f2b(X[i]);
        else      ((float*)out)[i] = X[i];
    }
}

extern "C" void kernel_launch(void* const* d_in, const int* in_sizes, int n_in,
                              void* d_out, int out_size, void* d_ws, size_t ws_size,
                              hipStream_t stream) {
    const int* targets = (const int*)d_in[0];
    const int* tlen    = (const int*)d_in[1];
    const void* enc    = d_in[2];
    const int* elen    = (const int*)d_in[3];
    const void* emb    = d_in[4];
    const void* W_in   = d_in[5];
    const void* b_in   = d_in[6];
    const void* ln1_g  = d_in[7];
    const void* ln1_b  = d_in[8];
    const void* Wq1 = d_in[9],  *bq1 = d_in[10];
    const void* Wk1 = d_in[11], *bk1 = d_in[12];
    const void* Wv1 = d_in[13], *bv1 = d_in[14];
    const void* Wo1 = d_in[15], *bo1 = d_in[16];
    const void* ln2_g = d_in[17], *ln2_b = d_in[18];
    const void* Wq2 = d_in[19], *bq2 = d_in[20];
    const void* Wk2 = d_in[21], *bk2 = d_in[22];
    const void* Wv2 = d_in[23], *bv2 = d_in[24];
    const void* Wo2 = d_in[25], *bo2 = d_in[26];
    const void* ln3_g = d_in[27], *ln3_b = d_in[28];
    const void* W_ff1 = d_in[29], *b_ff1 = d_in[30];
    const void* W_ff2 = d_in[31], *b_ff2 = d_in[32];
    const void* dt = ln1_g;

    float* ws  = (float*)d_ws;
    float* x   = ws;
    float* h   = ws + 2097152;
    float* q   = ws + 4194304;
    float* ctx = ws + 6291456;
    float* kb  = ws + 8388608;
    float* vb  = ws + 16777216;
    float* ffh = kb;

    const dim3 g64(8, 64);
    const dim3 gkv(8, 256);
    const dim3 gff1(32, 64);

    embed_kernel<<<4096, 256, 0, stream>>>(targets, emb, h, dt);
    gemm_kernel<false, false, false><<<g64, 256, 0, stream>>>(h, W_in, 0, b_in, 0, nullptr, x, 4096, 512, 512, dt);

    for (int l = 0; l < NL; ++l) {
        const size_t wo = (size_t)l * DM * DM;
        const size_t fo = (size_t)l * DM * DFF;
        const size_t vo = (size_t)l * DM;
        const size_t fv = (size_t)l * DFF;

        ln_kernel<<<4096, 256, 0, stream>>>(x, ln1_g, ln1_b, vo, h, dt);
        gemm_kernel<false, false, false><<<g64, 256, 0, stream>>>(h, Wq1, wo, bq1, vo, nullptr, q,  4096, 512, 512, dt);
        gemm_kernel<false, false, false><<<g64, 256, 0, stream>>>(h, Wk1, wo, bk1, vo, nullptr, kb, 4096, 512, 512, dt);
        gemm_kernel<false, false, false><<<g64, 256, 0, stream>>>(h, Wv1, wo, bv1, vo, nullptr, vb, 4096, 512, 512, dt);
        attn_kernel<<<BB * NH * TD, 64, 0, stream>>>(q, kb, vb, tlen, ctx, TD, TD, 1);
        gemm_kernel<false, false, true><<<g64, 256, 0, stream>>>(ctx, Wo1, wo, bo1, vo, x, x, 4096, 512, 512, dt);

        ln_kernel<<<4096, 256, 0, stream>>>(x, ln2_g, ln2_b, vo, h, dt);
        gemm_kernel<false, false, false><<<g64, 256, 0, stream>>>(h, Wq2, wo, bq2, vo, nullptr, q, 4096, 512, 512, dt);
        gemm_kernel<true, false, false><<<gkv, 256, 0, stream>>>(enc, Wk2, wo, bk2, vo, nullptr, kb, 16384, 512, 512, dt);
        gemm_kernel<true, false, false><<<gkv, 256, 0, stream>>>(enc, Wv2, wo, bv2, vo, nullptr, vb, 16384, 512, 512, dt);
        attn_kernel<<<BB * NH * TD, 64, 0, stream>>>(q, kb, vb, elen, ctx, TD, TE, 0);
        gemm_kernel<false, false, true><<<g64, 256, 0, stream>>>(ctx, Wo2, wo, bo2, vo, x, x, 4096, 512, 512, dt);

        ln_kernel<<<4096, 256, 0, stream>>>(x, ln3_g, ln3_b, vo, h, dt);
        gemm_kernel<false, true, false><<<gff1, 256, 0, stream>>>(h, W_ff1, fo, b_ff1, fv, nullptr, ffh, 4096, 2048, 512, dt);
        gemm_kernel<false, false, true><<<g64, 256, 0, stream>>>(ffh, W_ff2, fo, b_ff2, vo, x, x, 4096, 512, 2048, dt);
    }

    store_out_kernel<<<8192, 256, 0, stream>>>(x, d_out, BB * TD * DM, dt);
}

// Round 3
// 8273.541 us; speedup vs baseline: 2.3122x; 2.3122x over previous
//
#include <hip/hip_runtime.h>
#include <hip/hip_bf16.h>

#define BB   16
#define TD   256
#define TE   1024
#define DM   512
#define DFF  2048
#define NL   6
#define NH   8
#define DH   64

typedef unsigned short u16;

__device__ __forceinline__ float b2f(u16 u) {
    unsigned int x = ((unsigned int)u) << 16;
    float f;
    __builtin_memcpy(&f, &x, 4);
    return f;
}
__device__ __forceinline__ u16 f2b(float f) {
    unsigned int x;
    __builtin_memcpy(&x, &f, 4);
    unsigned int r = x + 0x7fffu + ((x >> 16) & 1u);
    return (u16)(r >> 16);
}

// dtype sentinel: ln1_g is all-ones. f32 word 0x3F800000 (low16==0); bf16 pair 0x3F803F80.
__device__ __forceinline__ int is_bf16(const void* dt) {
    return ((*(const unsigned int*)dt) & 0xFFFFu) != 0;
}

__device__ __forceinline__ float ld2(const void* pb, const void* pf, size_t i, int isbf) {
    return isbf ? b2f(((const u16*)pb)[i]) : ((const float*)pf)[i];
}
__device__ __forceinline__ void load4_2(const void* pb, const void* pf, size_t i, int isbf, float* a) {
    if (isbf) {
        ushort4 v = *reinterpret_cast<const ushort4*>((const u16*)pb + i);
        a[0] = b2f(v.x); a[1] = b2f(v.y); a[2] = b2f(v.z); a[3] = b2f(v.w);
    } else {
        float4 v = *reinterpret_cast<const float4*>((const float*)pf + i);
        a[0] = v.x; a[1] = v.y; a[2] = v.z; a[3] = v.w;
    }
}
__device__ __forceinline__ void load4f(const float* p, float* a) {
    const float4 v = *reinterpret_cast<const float4*>(p);
    a[0] = v.x; a[1] = v.y; a[2] = v.z; a[3] = v.w;
}

// ---------------- embedding + sinusoidal PE ----------------
__global__ __launch_bounds__(256) void embed_kernel(const int* __restrict__ targets,
                                                    const void* __restrict__ emb,
                                                    float* __restrict__ out,
                                                    const void* __restrict__ dt) {
    int isbf = is_bf16(dt);
    int row = blockIdx.x;
    int t   = row & (TD - 1);
    int tgt = targets[row];
    const float c = -0.017988946039015984f;   // -ln(10000)/512
    for (int d = threadIdx.x; d < DM; d += 256) {
        float e   = ld2(emb, emb, (size_t)tgt * DM + d, isbf) * 22.627416997969522f;
        int   i2  = d & ~1;
        float div = expf(c * (float)i2);
        float arg = (float)t * div;
        float pe  = (d & 1) ? cosf(arg) : sinf(arg);
        out[(size_t)row * DM + d] = e + pe;
    }
}

// ---------------- layernorm ----------------
__global__ __launch_bounds__(256) void ln_kernel(const float* __restrict__ X,
                                                 const void* __restrict__ g,
                                                 const void* __restrict__ b,
                                                 size_t vo,
                                                 float* __restrict__ O,
                                                 const void* __restrict__ dt) {
    int isbf = is_bf16(dt);
    int row = blockIdx.x;
    const float* xr = X + (size_t)row * DM;
    int tid = threadIdx.x;
    float v0 = xr[tid], v1 = xr[tid + 256];
    float s = v0 + v1;
    __shared__ float red[4];
    int lane = tid & 63, wid = tid >> 6;
#pragma unroll
    for (int off = 32; off; off >>= 1) s += __shfl_xor(s, off);
    if (lane == 0) red[wid] = s;
    __syncthreads();
    float mean = (red[0] + red[1] + red[2] + red[3]) * (1.0f / 512.0f);
    float d0 = v0 - mean, d1 = v1 - mean;
    float sq = d0 * d0 + d1 * d1;
#pragma unroll
    for (int off = 32; off; off >>= 1) sq += __shfl_xor(sq, off);
    __syncthreads();
    if (lane == 0) red[wid] = sq;
    __syncthreads();
    float var = (red[0] + red[1] + red[2] + red[3]) * (1.0f / 512.0f);
    float rs  = rsqrtf(var + 1e-5f);
    O[(size_t)row * DM + tid]       = d0 * rs * ld2(g, g, vo + tid, isbf)       + ld2(b, b, vo + tid, isbf);
    O[(size_t)row * DM + tid + 256] = d1 * rs * ld2(g, g, vo + tid + 256, isbf) + ld2(b, b, vo + tid + 256, isbf);
}

// ---------------- GEMM: C = act(A[MxK] @ W[KxN] + bias) (+resid) ----------------
template <bool AEXT, bool RELU, bool RES>
__global__ __launch_bounds__(256) void gemm_kernel(const void* __restrict__ A,
                                                   const void* __restrict__ W, size_t wofs,
                                                   const void* __restrict__ bias, size_t bofs,
                                                   const float* __restrict__ resid,
                                                   float* __restrict__ C,
                                                   int M, int N, int K,
                                                   const void* __restrict__ dt) {
    int isbf = is_bf16(dt);
    __shared__ float As[64][17];
    __shared__ float Bs[16][65];
    int tid  = threadIdx.x;
    int col0 = blockIdx.x * 64;
    int row0 = blockIdx.y * 64;
    int tx = tid & 15, ty = tid >> 4;
    float acc[4][4] = {};
    int ar = tid >> 2;
    int ak = (tid & 3) << 2;
    int wr = tid >> 4;
    int wn = (tid & 15) << 2;

    for (int k0 = 0; k0 < K; k0 += 16) {
        float av[4];
        if (AEXT) load4_2(A, A, (size_t)(row0 + ar) * K + k0 + ak, isbf, av);
        else      load4f((const float*)A + (size_t)(row0 + ar) * K + k0 + ak, av);
        As[ar][ak + 0] = av[0]; As[ar][ak + 1] = av[1];
        As[ar][ak + 2] = av[2]; As[ar][ak + 3] = av[3];
        float wv[4];
        load4_2(W, W, wofs + (size_t)(k0 + wr) * N + col0 + wn, isbf, wv);
        Bs[wr][wn + 0] = wv[0]; Bs[wr][wn + 1] = wv[1];
        Bs[wr][wn + 2] = wv[2]; Bs[wr][wn + 3] = wv[3];
        __syncthreads();
#pragma unroll
        for (int kk = 0; kk < 16; ++kk) {
            float a[4], bb[4];
#pragma unroll
            for (int i = 0; i < 4; ++i) a[i] = As[ty * 4 + i][kk];
#pragma unroll
            for (int j = 0; j < 4; ++j) bb[j] = Bs[kk][tx * 4 + j];
#pragma unroll
            for (int i = 0; i < 4; ++i)
#pragma unroll
                for (int j = 0; j < 4; ++j)
                    acc[i][j] = fmaf(a[i], bb[j], acc[i][j]);
        }
        __syncthreads();
    }
#pragma unroll
    for (int i = 0; i < 4; ++i) {
        int r = row0 + ty * 4 + i;
#pragma unroll
        for (int j = 0; j < 4; ++j) {
            int c = col0 + tx * 4 + j;
            float v = acc[i][j] + ld2(bias, bias, bofs + c, isbf);
            if (RES)  v += resid[(size_t)r * N + c];
            if (RELU) v = fmaxf(v, 0.0f);
            C[(size_t)r * N + c] = v;
        }
    }
}

// ---------------- tiled flash attention ----------------
// Block: 256 threads; grid (Tq/64, NH, BB). Q-tile 64, K-tile 64.
// Score pass: ty=tid>>4 -> 4 queries (ty*4+i), tx=tid&15 -> 4 keys (tx*4+j).
// PV pass:    ty -> same 4 queries,            tx -> 4 dims (tx*4+j).
#define LSTR 68   // LDS row stride (floats): 16B-aligned rows, spreads banks

__global__ __launch_bounds__(256) void fattn_kernel(const float* __restrict__ Q,
                                                    const float* __restrict__ K,
                                                    const float* __restrict__ V,
                                                    const int* __restrict__ lens,
                                                    float* __restrict__ O,
                                                    int Tq, int Tk, int causal) {
    __shared__ float Qs[DH][LSTR];   // transposed: [d][q]
    __shared__ float Ks[DH][LSTR];   // transposed: [d][k]
    __shared__ float Vs[64][LSTR];   // [k][d]
    __shared__ float Ps[64][LSTR];   // [q][k]
    int tid = threadIdx.x;
    int qt0 = blockIdx.x * 64;
    int h   = blockIdx.y;
    int b   = blockIdx.z;
    int len = lens[b];
    int tx  = tid & 15, ty = tid >> 4;

    // load Q tile (transposed into LDS), pre-scaled by 1/sqrt(dh)
    {
        int d = tid & 63;
        int q = tid >> 6;
#pragma unroll
        for (int i = 0; i < 64; i += 4) {
            int qq = q + i;
            Qs[d][qq] = Q[(size_t)(b * Tq + qt0 + qq) * DM + h * DH + d] * 0.125f;
        }
    }

    float Ow[4][4] = {};
    float m[4], l[4];
#pragma unroll
    for (int i = 0; i < 4; ++i) { m[i] = -1e30f; l[i] = 0.0f; }

    int kend = causal ? min(len, qt0 + 64) : len;
    for (int kt0 = 0; kt0 < kend; kt0 += 64) {
        __syncthreads();   // prev-tile Ps/Vs reads done before overwrite
        {
            int d = tid & 63;
            int k = tid >> 6;
#pragma unroll
            for (int i = 0; i < 64; i += 4) {
                int kk = k + i;
                int jk = kt0 + kk;
                float kv = 0.0f, vv = 0.0f;
                if (jk < Tk) {
                    kv = K[(size_t)(b * Tk + jk) * DM + h * DH + d];
                    vv = V[(size_t)(b * Tk + jk) * DM + h * DH + d];
                }
                Ks[d][kk] = kv;
                Vs[kk][d] = vv;
            }
        }
        __syncthreads();

        // scores s[i][j] = sum_d Qs[d][ty*4+i] * Ks[d][tx*4+j]
        float s[4][4] = {};
#pragma unroll 8
        for (int d = 0; d < DH; ++d) {
            float qa[4], ka[4];
            load4f(&Qs[d][ty * 4], qa);
            load4f(&Ks[d][tx * 4], ka);
#pragma unroll
            for (int i = 0; i < 4; ++i)
#pragma unroll
                for (int j = 0; j < 4; ++j)
                    s[i][j] = fmaf(qa[i], ka[j], s[i][j]);
        }

        // mask
#pragma unroll
        for (int j = 0; j < 4; ++j) {
            int jk = kt0 + tx * 4 + j;
            bool kinv = (jk >= len);
#pragma unroll
            for (int i = 0; i < 4; ++i) {
                bool inv = kinv || (causal && jk > qt0 + ty * 4 + i);
                if (inv) s[i][j] = -1e30f;
            }
        }

        // online softmax per query row (reduce across the 16-lane tx group)
#pragma unroll
        for (int i = 0; i < 4; ++i) {
            float rm = fmaxf(fmaxf(s[i][0], s[i][1]), fmaxf(s[i][2], s[i][3]));
#pragma unroll
            for (int off = 1; off < 16; off <<= 1) rm = fmaxf(rm, __shfl_xor(rm, off));
            float mn = fmaxf(m[i], rm);
            float alpha = __expf(m[i] - mn);
            m[i] = mn;
            float rs = 0.0f;
#pragma unroll
            for (int j = 0; j < 4; ++j) {
                s[i][j] = __expf(s[i][j] - mn);
                rs += s[i][j];
            }
#pragma unroll
            for (int off = 1; off < 16; off <<= 1) rs += __shfl_xor(rs, off);
            l[i] = l[i] * alpha + rs;
#pragma unroll
            for (int j = 0; j < 4; ++j) Ow[i][j] *= alpha;
            // write P row chunk (float4, aligned: LSTR%4==0)
            *reinterpret_cast<float4*>(&Ps[ty * 4 + i][tx * 4]) =
                make_float4(s[i][0], s[i][1], s[i][2], s[i][3]);
        }
        __syncthreads();

        // PV: Ow[i][j] += sum_k Ps[ty*4+i][k] * Vs[k][tx*4+j]
#pragma unroll 8
        for (int k = 0; k < 64; ++k) {
            float va[4];
            load4f(&Vs[k][tx * 4], va);
#pragma unroll
            for (int i = 0; i < 4; ++i) {
                float p = Ps[ty * 4 + i][k];
#pragma unroll
                for (int j = 0; j < 4; ++j)
                    Ow[i][j] = fmaf(p, va[j], Ow[i][j]);
            }
        }
    }

    // write O
#pragma unroll
    for (int i = 0; i < 4; ++i) {
        float inv = 1.0f / l[i];
        float4 o = make_float4(Ow[i][0] * inv, Ow[i][1] * inv, Ow[i][2] * inv, Ow[i][3] * inv);
        *reinterpret_cast<float4*>(
            &O[(size_t)(b * Tq + qt0 + ty * 4 + i) * DM + h * DH + tx * 4]) = o;
    }
}

// ---------------- f32 -> output ----------------
__global__ __launch_bounds__(256) void store_out_kernel(const float* __restrict__ X,
                                                        void* __restrict__ out, int n,
                                                        const void* __restrict__ dt) {
    int isbf = is_bf16(dt);
    int i = blockIdx.x * 256 + threadIdx.x;
    if (i < n) {
        if (isbf) ((u16*)out)[i] = f2b(X[i]);
        else      ((float*)out)[i] = X[i];
    }
}

extern "C" void kernel_launch(void* const* d_in, const int* in_sizes, int n_in,
                              void* d_out, int out_size, void* d_ws, size_t ws_size,
                              hipStream_t stream) {
    const int* targets = (const int*)d_in[0];
    const int* tlen    = (const int*)d_in[1];
    const void* enc    = d_in[2];
    const int* elen    = (const int*)d_in[3];
    const void* emb    = d_in[4];
    const void* W_in   = d_in[5];
    const void* b_in   = d_in[6];
    const void* ln1_g  = d_in[7];
    const void* ln1_b  = d_in[8];
    const void* Wq1 = d_in[9],  *bq1 = d_in[10];
    const void* Wk1 = d_in[11], *bk1 = d_in[12];
    const void* Wv1 = d_in[13], *bv1 = d_in[14];
    const void* Wo1 = d_in[15], *bo1 = d_in[16];
    const void* ln2_g = d_in[17], *ln2_b = d_in[18];
    const void* Wq2 = d_in[19], *bq2 = d_in[20];
    const void* Wk2 = d_in[21], *bk2 = d_in[22];
    const void* Wv2 = d_in[23], *bv2 = d_in[24];
    const void* Wo2 = d_in[25], *bo2 = d_in[26];
    const void* ln3_g = d_in[27], *ln3_b = d_in[28];
    const void* W_ff1 = d_in[29], *b_ff1 = d_in[30];
    const void* W_ff2 = d_in[31], *b_ff2 = d_in[32];
    const void* dt = ln1_g;

    float* ws  = (float*)d_ws;
    float* x   = ws;
    float* h   = ws + 2097152;
    float* q   = ws + 4194304;
    float* ctx = ws + 6291456;
    float* kb  = ws + 8388608;
    float* vb  = ws + 16777216;
    float* ffh = kb;

    const dim3 g64(8, 64);
    const dim3 gkv(8, 256);
    const dim3 gff1(32, 64);
    const dim3 gattn(TD / 64, NH, BB);

    embed_kernel<<<4096, 256, 0, stream>>>(targets, emb, h, dt);
    gemm_kernel<false, false, false><<<g64, 256, 0, stream>>>(h, W_in, 0, b_in, 0, nullptr, x, 4096, 512, 512, dt);

    for (int l = 0; l < NL; ++l) {
        const size_t wo = (size_t)l * DM * DM;
        const size_t fo = (size_t)l * DM * DFF;
        const size_t vo = (size_t)l * DM;
        const size_t fv = (size_t)l * DFF;

        ln_kernel<<<4096, 256, 0, stream>>>(x, ln1_g, ln1_b, vo, h, dt);
        gemm_kernel<false, false, false><<<g64, 256, 0, stream>>>(h, Wq1, wo, bq1, vo, nullptr, q,  4096, 512, 512, dt);
        gemm_kernel<false, false, false><<<g64, 256, 0, stream>>>(h, Wk1, wo, bk1, vo, nullptr, kb, 4096, 512, 512, dt);
        gemm_kernel<false, false, false><<<g64, 256, 0, stream>>>(h, Wv1, wo, bv1, vo, nullptr, vb, 4096, 512, 512, dt);
        fattn_kernel<<<gattn, 256, 0, stream>>>(q, kb, vb, tlen, ctx, TD, TD, 1);
        gemm_kernel<false, false, true><<<g64, 256, 0, stream>>>(ctx, Wo1, wo, bo1, vo, x, x, 4096, 512, 512, dt);

        ln_kernel<<<4096, 256, 0, stream>>>(x, ln2_g, ln2_b, vo, h, dt);
        gemm_kernel<false, false, false><<<g64, 256, 0, stream>>>(h, Wq2, wo, bq2, vo, nullptr, q, 4096, 512, 512, dt);
        gemm_kernel<true, false, false><<<gkv, 256, 0, stream>>>(enc, Wk2, wo, bk2, vo, nullptr, kb, 16384, 512, 512, dt);
        gemm_kernel<true, false, false><<<gkv, 256, 0, stream>>>(enc, Wv2, wo, bv2, vo, nullptr, vb, 16384, 512, 512, dt);
        fattn_kernel<<<gattn, 256, 0, stream>>>(q, kb, vb, elen, ctx, TD, TE, 0);
        gemm_kernel<false, false, true><<<g64, 256, 0, stream>>>(ctx, Wo2, wo, bo2, vo, x, x, 4096, 512, 512, dt);

        ln_kernel<<<4096, 256, 0, stream>>>(x, ln3_g, ln3_b, vo, h, dt);
        gemm_kernel<false, true, false><<<gff1, 256, 0, stream>>>(h, W_ff1, fo, b_ff1, fv, nullptr, ffh, 4096, 2048, 512, dt);
        gemm_kernel<false, false, true><<<g64, 256, 0, stream>>>(ffh, W_ff2, fo, b_ff2, vo, x, x, 4096, 512, 2048, dt);
    }

    store_out_kernel<<<8192, 256, 0, stream>>>(x, d_out, BB * TD * DM, dt);
}

// Round 5
// 3291.472 us; speedup vs baseline: 5.8121x; 2.5136x over previous
//
#include <hip/hip_runtime.h>
#include <hip/hip_bf16.h>

#define BB   16
#define TD   256
#define TE   1024
#define DM   512
#define DFF  2048
#define NL   6
#define NH   8
#define DH   64

typedef unsigned short u16;
typedef short short8 __attribute__((ext_vector_type(8)));
typedef float f32x4 __attribute__((ext_vector_type(4)));

__device__ __forceinline__ float b2f(u16 u) {
    unsigned int x = ((unsigned int)u) << 16;
    float f;
    __builtin_memcpy(&f, &x, 4);
    return f;
}
__device__ __forceinline__ u16 f2b(float f) {           // round-to-nearest-even
    unsigned int x;
    __builtin_memcpy(&x, &f, 4);
    unsigned int r = x + 0x7fffu + ((x >> 16) & 1u);
    return (u16)(r >> 16);
}
__device__ __forceinline__ void load4f(const float* p, float* a) {
    const float4 v = *reinterpret_cast<const float4*>(p);
    a[0] = v.x; a[1] = v.y; a[2] = v.z; a[3] = v.w;
}

// ---------------- f32 -> bf16 bulk convert (enc) ----------------
__global__ __launch_bounds__(256) void cvt_kernel(const float* __restrict__ in,
                                                  u16* __restrict__ out, int n4) {
    int i = blockIdx.x * 256 + threadIdx.x;
    if (i < n4) {
        float4 v = reinterpret_cast<const float4*>(in)[i];
        ushort4 o;
        o.x = f2b(v.x); o.y = f2b(v.y); o.z = f2b(v.z); o.w = f2b(v.w);
        reinterpret_cast<ushort4*>(out)[i] = o;
    }
}

// ---------------- embedding + sinusoidal PE -> bf16 ----------------
__global__ __launch_bounds__(256) void embed_kernel(const int* __restrict__ targets,
                                                    const float* __restrict__ emb,
                                                    u16* __restrict__ out) {
    int row = blockIdx.x;
    int t   = row & (TD - 1);
    int tgt = targets[row];
    const float c = -0.017988946039015984f;   // -ln(10000)/512
    for (int d = threadIdx.x; d < DM; d += 256) {
        float e   = emb[(size_t)tgt * DM + d] * 22.627416997969522f;  // sqrt(512)
        int   i2  = d & ~1;
        float div = expf(c * (float)i2);
        float arg = (float)t * div;
        float pe  = (d & 1) ? cosf(arg) : sinf(arg);
        out[(size_t)row * DM + d] = f2b(e + pe);
    }
}

// ---------------- layernorm: f32 in -> bf16 out ----------------
__global__ __launch_bounds__(256) void ln_kernel(const float* __restrict__ X,
                                                 const float* __restrict__ g,
                                                 const float* __restrict__ b,
                                                 size_t vo,
                                                 u16* __restrict__ O) {
    int row = blockIdx.x;
    const float* xr = X + (size_t)row * DM;
    int tid = threadIdx.x;
    float v0 = xr[tid], v1 = xr[tid + 256];
    float s = v0 + v1;
    __shared__ float red[4];
    int lane = tid & 63, wid = tid >> 6;
#pragma unroll
    for (int off = 32; off; off >>= 1) s += __shfl_xor(s, off);
    if (lane == 0) red[wid] = s;
    __syncthreads();
    float mean = (red[0] + red[1] + red[2] + red[3]) * (1.0f / 512.0f);
    float d0 = v0 - mean, d1 = v1 - mean;
    float sq = d0 * d0 + d1 * d1;
#pragma unroll
    for (int off = 32; off; off >>= 1) sq += __shfl_xor(sq, off);
    __syncthreads();
    if (lane == 0) red[wid] = sq;
    __syncthreads();
    float var = (red[0] + red[1] + red[2] + red[3]) * (1.0f / 512.0f);
    float rs  = rsqrtf(var + 1e-5f);
    O[(size_t)row * DM + tid]       = f2b(d0 * rs * g[vo + tid]       + b[vo + tid]);
    O[(size_t)row * DM + tid + 256] = f2b(d1 * rs * g[vo + tid + 256] + b[vo + tid + 256]);
}

// ---------------- MFMA GEMM: C = act(A[MxK]bf16 @ W[KxN]f32 + bias) (+resid) -----
// 128x128 tile, BK=32, 256 thr = 4 waves (2x2), each wave 64x64 via 4x4 mfma 16x16x32.
// A staged [m][k] bf16 (stride 40: 2-way conflict = free); W converted+transposed
// to Bs[n][k] bf16 during staging. fp32 accumulate; epilogue bias/relu/resid.
#define ASTR 40

template <bool OUTBF, bool RELU, bool RES>
__global__ __launch_bounds__(256) void gemm_mfma(const u16* __restrict__ A,
                                                 const float* __restrict__ W, size_t wofs,
                                                 const float* __restrict__ bias, size_t bofs,
                                                 const float* __restrict__ resid,
                                                 void* __restrict__ C,
                                                 int M, int N, int K) {
    __shared__ u16 As[128 * ASTR];
    __shared__ u16 Bs[128 * ASTR];
    int tid  = threadIdx.x;
    int col0 = blockIdx.x * 128;
    int row0 = blockIdx.y * 128;

    int am   = tid >> 1;            // A stage: row 0..127
    int ah   = (tid & 1) * 16;      // k-half 0/16
    int kk   = tid >> 3;            // W stage: k row 0..31
    int nq   = (tid & 7) * 4;       // W stage: n quad base

    int wave = tid >> 6, lane = tid & 63;
    int wm = (wave >> 1) * 64, wn = (wave & 1) * 64;
    int lq = lane >> 4, lc = lane & 15;

    f32x4 acc[4][4] = {};

    for (int k0 = 0; k0 < K; k0 += 32) {
        // stage A: 128x32 bf16
        const uint4* pa = reinterpret_cast<const uint4*>(A + (size_t)(row0 + am) * K + k0 + ah);
        uint4 a0 = pa[0], a1 = pa[1];
        *reinterpret_cast<uint4*>(&As[am * ASTR + ah])     = a0;
        *reinterpret_cast<uint4*>(&As[am * ASTR + ah + 8]) = a1;
        // stage W: 32x128 f32 -> Bs[n][k] bf16 (transpose + convert)
#pragma unroll
        for (int it = 0; it < 4; ++it) {
            int n0 = nq + it * 32;
            float4 wv = *reinterpret_cast<const float4*>(W + wofs + (size_t)(k0 + kk) * N + col0 + n0);
            Bs[(n0 + 0) * ASTR + kk] = f2b(wv.x);
            Bs[(n0 + 1) * ASTR + kk] = f2b(wv.y);
            Bs[(n0 + 2) * ASTR + kk] = f2b(wv.z);
            Bs[(n0 + 3) * ASTR + kk] = f2b(wv.w);
        }
        __syncthreads();

        short8 af[4], bf[4];
#pragma unroll
        for (int i = 0; i < 4; ++i)
            af[i] = *reinterpret_cast<const short8*>(&As[(wm + i * 16 + lc) * ASTR + lq * 8]);
#pragma unroll
        for (int j = 0; j < 4; ++j)
            bf[j] = *reinterpret_cast<const short8*>(&Bs[(wn + j * 16 + lc) * ASTR + lq * 8]);
#pragma unroll
        for (int i = 0; i < 4; ++i)
#pragma unroll
            for (int j = 0; j < 4; ++j)
                acc[i][j] = __builtin_amdgcn_mfma_f32_16x16x32_bf16(af[i], bf[j], acc[i][j], 0, 0, 0);
        __syncthreads();
    }

    // epilogue: C/D layout col=lane&15, row=quad*4+reg
#pragma unroll
    for (int j = 0; j < 4; ++j) {
        int n = col0 + wn + j * 16 + lc;
        float bv = bias[bofs + n];
#pragma unroll
        for (int i = 0; i < 4; ++i) {
#pragma unroll
            for (int r = 0; r < 4; ++r) {
                int m = row0 + wm + i * 16 + lq * 4 + r;
                float v = acc[i][j][r] + bv;
                if (RES)  v += resid[(size_t)m * N + n];
                if (RELU) v = fmaxf(v, 0.0f);
                if (OUTBF) ((u16*)C)[(size_t)m * N + n] = f2b(v);
                else       ((float*)C)[(size_t)m * N + n] = v;
            }
        }
    }
}

// ---------------- tiled flash attention (bf16 in/out, f32 math) ----------------
#define LSTR 68

__global__ __launch_bounds__(256) void fattn_kernel(const u16* __restrict__ Q,
                                                    const u16* __restrict__ K,
                                                    const u16* __restrict__ V,
                                                    const int* __restrict__ lens,
                                                    u16* __restrict__ O,
                                                    int Tq, int Tk, int causal) {
    __shared__ float Qs[DH][LSTR];   // [d][q]
    __shared__ float Ks[DH][LSTR];   // [d][k]
    __shared__ float Vs[64][LSTR];   // [k][d]
    __shared__ float Ps[64][LSTR];   // [q][k]
    int tid = threadIdx.x;
    int qt0 = blockIdx.x * 64;
    int h   = blockIdx.y;
    int b   = blockIdx.z;
    int len = lens[b];
    int tx  = tid & 15, ty = tid >> 4;

    {
        int d = tid & 63;
        int q = tid >> 6;
#pragma unroll
        for (int i = 0; i < 64; i += 4) {
            int qq = q + i;
            Qs[d][qq] = b2f(Q[(size_t)(b * Tq + qt0 + qq) * DM + h * DH + d]) * 0.125f;
        }
    }

    float Ow[4][4] = {};
    float m[4], l[4];
#pragma unroll
    for (int i = 0; i < 4; ++i) { m[i] = -1e30f; l[i] = 0.0f; }

    int kend = causal ? min(len, qt0 + 64) : len;
    for (int kt0 = 0; kt0 < kend; kt0 += 64) {
        __syncthreads();
        {
            int d = tid & 63;
            int k = tid >> 6;
#pragma unroll
            for (int i = 0; i < 64; i += 4) {
                int kk = k + i;
                int jk = kt0 + kk;
                float kv = 0.0f, vv = 0.0f;
                if (jk < Tk) {
                    kv = b2f(K[(size_t)(b * Tk + jk) * DM + h * DH + d]);
                    vv = b2f(V[(size_t)(b * Tk + jk) * DM + h * DH + d]);
                }
                Ks[d][kk] = kv;
                Vs[kk][d] = vv;
            }
        }
        __syncthreads();

        float s[4][4] = {};
#pragma unroll 8
        for (int d = 0; d < DH; ++d) {
            float qa[4], ka[4];
            load4f(&Qs[d][ty * 4], qa);
            load4f(&Ks[d][tx * 4], ka);
#pragma unroll
            for (int i = 0; i < 4; ++i)
#pragma unroll
                for (int j = 0; j < 4; ++j)
                    s[i][j] = fmaf(qa[i], ka[j], s[i][j]);
        }

#pragma unroll
        for (int j = 0; j < 4; ++j) {
            int jk = kt0 + tx * 4 + j;
            bool kinv = (jk >= len);
#pragma unroll
            for (int i = 0; i < 4; ++i) {
                bool inv = kinv || (causal && jk > qt0 + ty * 4 + i);
                if (inv) s[i][j] = -1e30f;
            }
        }

#pragma unroll
        for (int i = 0; i < 4; ++i) {
            float rm = fmaxf(fmaxf(s[i][0], s[i][1]), fmaxf(s[i][2], s[i][3]));
#pragma unroll
            for (int off = 1; off < 16; off <<= 1) rm = fmaxf(rm, __shfl_xor(rm, off));
            float mn = fmaxf(m[i], rm);
            float alpha = __expf(m[i] - mn);
            m[i] = mn;
            float rs = 0.0f;
#pragma unroll
            for (int j = 0; j < 4; ++j) {
                s[i][j] = __expf(s[i][j] - mn);
                rs += s[i][j];
            }
#pragma unroll
            for (int off = 1; off < 16; off <<= 1) rs += __shfl_xor(rs, off);
            l[i] = l[i] * alpha + rs;
#pragma unroll
            for (int j = 0; j < 4; ++j) Ow[i][j] *= alpha;
            *reinterpret_cast<float4*>(&Ps[ty * 4 + i][tx * 4]) =
                make_float4(s[i][0], s[i][1], s[i][2], s[i][3]);
        }
        __syncthreads();

#pragma unroll 8
        for (int k = 0; k < 64; ++k) {
            float va[4];
            load4f(&Vs[k][tx * 4], va);
#pragma unroll
            for (int i = 0; i < 4; ++i) {
                float p = Ps[ty * 4 + i][k];
#pragma unroll
                for (int j = 0; j < 4; ++j)
                    Ow[i][j] = fmaf(p, va[j], Ow[i][j]);
            }
        }
    }

#pragma unroll
    for (int i = 0; i < 4; ++i) {
        float inv = 1.0f / l[i];
        ushort4 o;
        o.x = f2b(Ow[i][0] * inv); o.y = f2b(Ow[i][1] * inv);
        o.z = f2b(Ow[i][2] * inv); o.w = f2b(Ow[i][3] * inv);
        *reinterpret_cast<ushort4*>(
            &O[(size_t)(b * Tq + qt0 + ty * 4 + i) * DM + h * DH + tx * 4]) = o;
    }
}

// ---------------- f32 -> f32 output (harness decodes d_out as float32!) --------
__global__ __launch_bounds__(256) void store_out_kernel(const float* __restrict__ X,
                                                        float* __restrict__ out, int n) {
    int i = blockIdx.x * 256 + threadIdx.x;
    if (i < n) out[i] = X[i];
}

extern "C" void kernel_launch(void* const* d_in, const int* in_sizes, int n_in,
                              void* d_out, int out_size, void* d_ws, size_t ws_size,
                              hipStream_t stream) {
    const int*   targets = (const int*)d_in[0];
    const int*   tlen    = (const int*)d_in[1];
    const float* enc     = (const float*)d_in[2];
    const int*   elen    = (const int*)d_in[3];
    const float* emb     = (const float*)d_in[4];
    const float* W_in    = (const float*)d_in[5];
    const float* b_in    = (const float*)d_in[6];
    const float* ln1_g   = (const float*)d_in[7];
    const float* ln1_b   = (const float*)d_in[8];
    const float* Wq1 = (const float*)d_in[9],  *bq1 = (const float*)d_in[10];
    const float* Wk1 = (const float*)d_in[11], *bk1 = (const float*)d_in[12];
    const float* Wv1 = (const float*)d_in[13], *bv1 = (const float*)d_in[14];
    const float* Wo1 = (const float*)d_in[15], *bo1 = (const float*)d_in[16];
    const float* ln2_g = (const float*)d_in[17], *ln2_b = (const float*)d_in[18];
    const float* Wq2 = (const float*)d_in[19], *bq2 = (const float*)d_in[20];
    const float* Wk2 = (const float*)d_in[21], *bk2 = (const float*)d_in[22];
    const float* Wv2 = (const float*)d_in[23], *bv2 = (const float*)d_in[24];
    const float* Wo2 = (const float*)d_in[25], *bo2 = (const float*)d_in[26];
    const float* ln3_g = (const float*)d_in[27], *ln3_b = (const float*)d_in[28];
    const float* W_ff1 = (const float*)d_in[29], *b_ff1 = (const float*)d_in[30];
    const float* W_ff2 = (const float*)d_in[31], *b_ff2 = (const float*)d_in[32];

    float* ws   = (float*)d_ws;
    float* x    = ws;                              // [0,8M)   4096x512 f32
    u16*   hb   = (u16*)(ws + 2097152);            // [8,12M)  4096x512 bf16
    u16*   qb   = (u16*)(ws + 3145728);            // [12,16M) 4096x512 bf16
    u16*   ctx  = (u16*)(ws + 4194304);            // [16,20M) 4096x512 bf16
    u16*   kb   = (u16*)(ws + 5242880);            // [20,36M) 16384x512 bf16
    u16*   vb   = (u16*)(ws + 9437184);            // [36,52M) 16384x512 bf16
    u16*   encb = (u16*)(ws + 13631488);           // [52,68M) 16384x512 bf16
    u16*   ffh  = kb;                              // 4096x2048 bf16 (aliases kb)

    const dim3 gdm(4, 32);     // M=4096,  N=512
    const dim3 gkv(4, 128);    // M=16384, N=512
    const dim3 gf1(16, 32);    // M=4096,  N=2048
    const dim3 gattn(TD / 64, NH, BB);

    cvt_kernel<<<8192, 256, 0, stream>>>(enc, encb, BB * TE * DM / 4);
    embed_kernel<<<4096, 256, 0, stream>>>(targets, emb, hb);
    gemm_mfma<false, false, false><<<gdm, 256, 0, stream>>>(hb, W_in, 0, b_in, 0, nullptr, x, 4096, 512, 512);

    for (int l = 0; l < NL; ++l) {
        const size_t wo = (size_t)l * DM * DM;
        const size_t fo = (size_t)l * DM * DFF;
        const size_t vo = (size_t)l * DM;
        const size_t fv = (size_t)l * DFF;

        ln_kernel<<<4096, 256, 0, stream>>>(x, ln1_g, ln1_b, vo, hb);
        gemm_mfma<true, false, false><<<gdm, 256, 0, stream>>>(hb, Wq1, wo, bq1, vo, nullptr, qb, 4096, 512, 512);
        gemm_mfma<true, false, false><<<gdm, 256, 0, stream>>>(hb, Wk1, wo, bk1, vo, nullptr, kb, 4096, 512, 512);
        gemm_mfma<true, false, false><<<gdm, 256, 0, stream>>>(hb, Wv1, wo, bv1, vo, nullptr, vb, 4096, 512, 512);
        fattn_kernel<<<gattn, 256, 0, stream>>>(qb, kb, vb, tlen, ctx, TD, TD, 1);
        gemm_mfma<false, false, true><<<gdm, 256, 0, stream>>>(ctx, Wo1, wo, bo1, vo, x, x, 4096, 512, 512);

        ln_kernel<<<4096, 256, 0, stream>>>(x, ln2_g, ln2_b, vo, hb);
        gemm_mfma<true, false, false><<<gdm, 256, 0, stream>>>(hb, Wq2, wo, bq2, vo, nullptr, qb, 4096, 512, 512);
        gemm_mfma<true, false, false><<<gkv, 256, 0, stream>>>(encb, Wk2, wo, bk2, vo, nullptr, kb, 16384, 512, 512);
        gemm_mfma<true, false, false><<<gkv, 256, 0, stream>>>(encb, Wv2, wo, bv2, vo, nullptr, vb, 16384, 512, 512);
        fattn_kernel<<<gattn, 256, 0, stream>>>(qb, kb, vb, elen, ctx, TD, TE, 0);
        gemm_mfma<false, false, true><<<gdm, 256, 0, stream>>>(ctx, Wo2, wo, bo2, vo, x, x, 4096, 512, 512);

        ln_kernel<<<4096, 256, 0, stream>>>(x, ln3_g, ln3_b, vo, hb);
        gemm_mfma<true, true, false><<<gf1, 256, 0, stream>>>(hb, W_ff1, fo, b_ff1, fv, nullptr, ffh, 4096, 2048, 512);
        gemm_mfma<false, false, true><<<gdm, 256, 0, stream>>>(ffh, W_ff2, fo, b_ff2, vo, x, x, 4096, 512, 2048);
    }

    store_out_kernel<<<8192, 256, 0, stream>>>(x, (float*)d_out, BB * TD * DM);
}

// Round 6
// 2473.443 us; speedup vs baseline: 7.7343x; 1.3307x over previous
//
#include <hip/hip_runtime.h>
#include <hip/hip_bf16.h>

#define BB   16
#define TD   256
#define TE   1024
#define DM   512
#define DFF  2048
#define NL   6
#define NH   8
#define DH   64

typedef unsigned short u16;
typedef short short8 __attribute__((ext_vector_type(8)));
typedef float f32x4 __attribute__((ext_vector_type(4)));

__device__ __forceinline__ float b2f(u16 u) {
    unsigned int x = ((unsigned int)u) << 16;
    float f;
    __builtin_memcpy(&f, &x, 4);
    return f;
}
__device__ __forceinline__ u16 f2b(float f) {           // round-to-nearest-even
    unsigned int x;
    __builtin_memcpy(&x, &f, 4);
    unsigned int r = x + 0x7fffu + ((x >> 16) & 1u);
    return (u16)(r >> 16);
}

// ---------------- f32 -> bf16 bulk convert (enc) ----------------
__global__ __launch_bounds__(256) void cvt_kernel(const float* __restrict__ in,
                                                  u16* __restrict__ out, int n4) {
    int i = blockIdx.x * 256 + threadIdx.x;
    if (i < n4) {
        float4 v = reinterpret_cast<const float4*>(in)[i];
        ushort4 o;
        o.x = f2b(v.x); o.y = f2b(v.y); o.z = f2b(v.z); o.w = f2b(v.w);
        reinterpret_cast<ushort4*>(out)[i] = o;
    }
}

// ---------------- embedding + sinusoidal PE -> bf16 ----------------
__global__ __launch_bounds__(256) void embed_kernel(const int* __restrict__ targets,
                                                    const float* __restrict__ emb,
                                                    u16* __restrict__ out) {
    int row = blockIdx.x;
    int t   = row & (TD - 1);
    int tgt = targets[row];
    const float c = -0.017988946039015984f;   // -ln(10000)/512
    for (int d = threadIdx.x; d < DM; d += 256) {
        float e   = emb[(size_t)tgt * DM + d] * 22.627416997969522f;  // sqrt(512)
        int   i2  = d & ~1;
        float div = expf(c * (float)i2);
        float arg = (float)t * div;
        float pe  = (d & 1) ? cosf(arg) : sinf(arg);
        out[(size_t)row * DM + d] = f2b(e + pe);
    }
}

// ---------------- layernorm: f32 in -> bf16 out ----------------
__global__ __launch_bounds__(256) void ln_kernel(const float* __restrict__ X,
                                                 const float* __restrict__ g,
                                                 const float* __restrict__ b,
                                                 size_t vo,
                                                 u16* __restrict__ O) {
    int row = blockIdx.x;
    const float* xr = X + (size_t)row * DM;
    int tid = threadIdx.x;
    float v0 = xr[tid], v1 = xr[tid + 256];
    float s = v0 + v1;
    __shared__ float red[4];
    int lane = tid & 63, wid = tid >> 6;
#pragma unroll
    for (int off = 32; off; off >>= 1) s += __shfl_xor(s, off);
    if (lane == 0) red[wid] = s;
    __syncthreads();
    float mean = (red[0] + red[1] + red[2] + red[3]) * (1.0f / 512.0f);
    float d0 = v0 - mean, d1 = v1 - mean;
    float sq = d0 * d0 + d1 * d1;
#pragma unroll
    for (int off = 32; off; off >>= 1) sq += __shfl_xor(sq, off);
    __syncthreads();
    if (lane == 0) red[wid] = sq;
    __syncthreads();
    float var = (red[0] + red[1] + red[2] + red[3]) * (1.0f / 512.0f);
    float rs  = rsqrtf(var + 1e-5f);
    O[(size_t)row * DM + tid]       = f2b(d0 * rs * g[vo + tid]       + b[vo + tid]);
    O[(size_t)row * DM + tid + 256] = f2b(d1 * rs * g[vo + tid + 256] + b[vo + tid + 256]);
}

// ---------------- MFMA GEMM (unchanged from round 5) ----------------
#define ASTR 40

template <bool OUTBF, bool RELU, bool RES>
__global__ __launch_bounds__(256) void gemm_mfma(const u16* __restrict__ A,
                                                 const float* __restrict__ W, size_t wofs,
                                                 const float* __restrict__ bias, size_t bofs,
                                                 const float* __restrict__ resid,
                                                 void* __restrict__ C,
                                                 int M, int N, int K) {
    __shared__ u16 As[128 * ASTR];
    __shared__ u16 Bs[128 * ASTR];
    int tid  = threadIdx.x;
    int col0 = blockIdx.x * 128;
    int row0 = blockIdx.y * 128;

    int am   = tid >> 1;
    int ah   = (tid & 1) * 16;
    int kk   = tid >> 3;
    int nq   = (tid & 7) * 4;

    int wave = tid >> 6, lane = tid & 63;
    int wm = (wave >> 1) * 64, wn = (wave & 1) * 64;
    int lq = lane >> 4, lc = lane & 15;

    f32x4 acc[4][4] = {};

    for (int k0 = 0; k0 < K; k0 += 32) {
        const uint4* pa = reinterpret_cast<const uint4*>(A + (size_t)(row0 + am) * K + k0 + ah);
        uint4 a0 = pa[0], a1 = pa[1];
        *reinterpret_cast<uint4*>(&As[am * ASTR + ah])     = a0;
        *reinterpret_cast<uint4*>(&As[am * ASTR + ah + 8]) = a1;
#pragma unroll
        for (int it = 0; it < 4; ++it) {
            int n0 = nq + it * 32;
            float4 wv = *reinterpret_cast<const float4*>(W + wofs + (size_t)(k0 + kk) * N + col0 + n0);
            Bs[(n0 + 0) * ASTR + kk] = f2b(wv.x);
            Bs[(n0 + 1) * ASTR + kk] = f2b(wv.y);
            Bs[(n0 + 2) * ASTR + kk] = f2b(wv.z);
            Bs[(n0 + 3) * ASTR + kk] = f2b(wv.w);
        }
        __syncthreads();

        short8 af[4], bf[4];
#pragma unroll
        for (int i = 0; i < 4; ++i)
            af[i] = *reinterpret_cast<const short8*>(&As[(wm + i * 16 + lc) * ASTR + lq * 8]);
#pragma unroll
        for (int j = 0; j < 4; ++j)
            bf[j] = *reinterpret_cast<const short8*>(&Bs[(wn + j * 16 + lc) * ASTR + lq * 8]);
#pragma unroll
        for (int i = 0; i < 4; ++i)
#pragma unroll
            for (int j = 0; j < 4; ++j)
                acc[i][j] = __builtin_amdgcn_mfma_f32_16x16x32_bf16(af[i], bf[j], acc[i][j], 0, 0, 0);
        __syncthreads();
    }

#pragma unroll
    for (int j = 0; j < 4; ++j) {
        int n = col0 + wn + j * 16 + lc;
        float bv = bias[bofs + n];
#pragma unroll
        for (int i = 0; i < 4; ++i) {
#pragma unroll
            for (int r = 0; r < 4; ++r) {
                int m = row0 + wm + i * 16 + lq * 4 + r;
                float v = acc[i][j][r] + bv;
                if (RES)  v += resid[(size_t)m * N + n];
                if (RELU) v = fmaxf(v, 0.0f);
                if (OUTBF) ((u16*)C)[(size_t)m * N + n] = f2b(v);
                else       ((float*)C)[(size_t)m * N + n] = v;
            }
        }
    }
}

// ---------------- MFMA flash attention ----------------
// Block = 256 thr (4 waves), grid (Tq/64, NH, BB). 64-query tile per block,
// 64-key K-tiles. Wave w owns queries [w*16, w*16+16).
// S-pass: A=Q[q][d], B=K[key][d]; C rows = quad*4+reg -> per-reg softmax state,
// 16-lane xor reduce. P -> LDS (C-layout) -> reread as A by the SAME wave.
// V transposed at staging into Vs[d][key] (stride 66; b32 frag reads).
#define QSTR 72
#define VSTR 66

__global__ __launch_bounds__(256) void fattn_mfma(const u16* __restrict__ Q,
                                                  const u16* __restrict__ K,
                                                  const u16* __restrict__ V,
                                                  const int* __restrict__ lens,
                                                  u16* __restrict__ O,
                                                  int Tq, int Tk, int causal) {
    __shared__ u16 Qs[64 * QSTR];
    __shared__ u16 Ks[64 * QSTR];
    __shared__ u16 Ps[64 * QSTR];
    __shared__ u16 Vs[64 * VSTR];
    int tid  = threadIdx.x;
    int qt0  = blockIdx.x * 64;
    int h    = blockIdx.y;
    int b    = blockIdx.z;
    int len  = lens[b];
    int wave = tid >> 6, lane = tid & 63;
    int lq = lane >> 4, lc = lane & 15;
    int sr = tid >> 4;              // staging row 0..15
    int sd = (tid & 15) * 4;        // staging d 0,4,..,60

    // stage Q once, pre-scaled by 1/sqrt(64) = 2^-3 (exact in bf16)
#pragma unroll
    for (int i = 0; i < 4; ++i) {
        int q = sr + i * 16;
        ushort4 v = *reinterpret_cast<const ushort4*>(
            &Q[(size_t)(b * Tq + qt0 + q) * DM + h * DH + sd]);
        ushort4 w;
        w.x = f2b(b2f(v.x) * 0.125f); w.y = f2b(b2f(v.y) * 0.125f);
        w.z = f2b(b2f(v.z) * 0.125f); w.w = f2b(b2f(v.w) * 0.125f);
        *reinterpret_cast<ushort4*>(&Qs[q * QSTR + sd]) = w;
    }
    __syncthreads();

    // hoisted Q A-frags (rows wave*16 + lc)
    short8 aq0 = *reinterpret_cast<const short8*>(&Qs[(wave * 16 + lc) * QSTR + lq * 8]);
    short8 aq1 = *reinterpret_cast<const short8*>(&Qs[(wave * 16 + lc) * QSTR + 32 + lq * 8]);

    f32x4 Ow[4] = {};
    float m[4], l[4];
#pragma unroll
    for (int r = 0; r < 4; ++r) { m[r] = -1e30f; l[r] = 0.0f; }

    int kend = causal ? min(len, qt0 + 64) : len;
    for (int kt0 = 0; kt0 < kend; kt0 += 64) {
        __syncthreads();   // prev PV reads of Ks/Vs/Ps done before restage
#pragma unroll
        for (int i = 0; i < 4; ++i) {
            int k = sr + i * 16;
            ushort4 kv = *reinterpret_cast<const ushort4*>(
                &K[(size_t)(b * Tk + kt0 + k) * DM + h * DH + sd]);
            *reinterpret_cast<ushort4*>(&Ks[k * QSTR + sd]) = kv;
            ushort4 vv = *reinterpret_cast<const ushort4*>(
                &V[(size_t)(b * Tk + kt0 + k) * DM + h * DH + sd]);
            Vs[(sd + 0) * VSTR + k] = vv.x;
            Vs[(sd + 1) * VSTR + k] = vv.y;
            Vs[(sd + 2) * VSTR + k] = vv.z;
            Vs[(sd + 3) * VSTR + k] = vv.w;
        }
        __syncthreads();

        // S = Q K^T : 4 n-tiles x 2 k-steps
        f32x4 sa[4] = {};
#pragma unroll
        for (int n = 0; n < 4; ++n) {
            short8 bk0 = *reinterpret_cast<const short8*>(&Ks[(n * 16 + lc) * QSTR + lq * 8]);
            short8 bk1 = *reinterpret_cast<const short8*>(&Ks[(n * 16 + lc) * QSTR + 32 + lq * 8]);
            sa[n] = __builtin_amdgcn_mfma_f32_16x16x32_bf16(aq0, bk0, sa[n], 0, 0, 0);
            sa[n] = __builtin_amdgcn_mfma_f32_16x16x32_bf16(aq1, bk1, sa[n], 0, 0, 0);
        }

        // mask + online softmax per row (row = quad*4 + r)
        int qrow_base = qt0 + wave * 16 + lq * 4;
#pragma unroll
        for (int r = 0; r < 4; ++r) {
            int qrow = qrow_base + r;
            float sv[4];
#pragma unroll
            for (int n = 0; n < 4; ++n) {
                int key = kt0 + n * 16 + lc;
                bool inv = (key >= len) || (causal && key > qrow);
                sv[n] = inv ? -1e30f : sa[n][r];
            }
            float rm = fmaxf(fmaxf(sv[0], sv[1]), fmaxf(sv[2], sv[3]));
#pragma unroll
            for (int off = 1; off < 16; off <<= 1) rm = fmaxf(rm, __shfl_xor(rm, off));
            float mn = fmaxf(m[r], rm);
            float alpha = __expf(m[r] - mn);
            m[r] = mn;
            float rs = 0.0f;
#pragma unroll
            for (int n = 0; n < 4; ++n) {
                float p = __expf(sv[n] - mn);
                rs += p;
                Ps[(wave * 16 + lq * 4 + r) * QSTR + n * 16 + lc] = f2b(p);
            }
#pragma unroll
            for (int off = 1; off < 16; off <<= 1) rs += __shfl_xor(rs, off);
            l[r] = l[r] * alpha + rs;
#pragma unroll
            for (int n = 0; n < 4; ++n) Ow[n][r] *= alpha;
        }
        __syncthreads();   // Ps visible (cheap safety; also orders Vs reads)

        // PV: A = P rows (same wave), B = Vs[d][key]
        short8 ap0 = *reinterpret_cast<const short8*>(&Ps[(wave * 16 + lc) * QSTR + lq * 8]);
        short8 ap1 = *reinterpret_cast<const short8*>(&Ps[(wave * 16 + lc) * QSTR + 32 + lq * 8]);
#pragma unroll
        for (int n = 0; n < 4; ++n) {
#pragma unroll
            for (int ks = 0; ks < 2; ++ks) {
                int base = (n * 16 + lc) * VSTR + ks * 32 + lq * 8;   // even -> 4B aligned
                const int* vp = reinterpret_cast<const int*>(&Vs[base]);
                int w[4] = { vp[0], vp[1], vp[2], vp[3] };
                short8 bv;
                __builtin_memcpy(&bv, w, 16);
                Ow[n] = __builtin_amdgcn_mfma_f32_16x16x32_bf16(ks ? ap1 : ap0, bv, Ow[n], 0, 0, 0);
            }
        }
    }

    // write O (C-layout scatter; consecutive lanes -> consecutive d)
#pragma unroll
    for (int r = 0; r < 4; ++r) {
        float inv = 1.0f / l[r];
        size_t rowoff = (size_t)(b * Tq + qt0 + wave * 16 + lq * 4 + r) * DM + h * DH;
#pragma unroll
        for (int n = 0; n < 4; ++n)
            O[rowoff + n * 16 + lc] = f2b(Ow[n][r] * inv);
    }
}

// ---------------- f32 -> f32 output ----------------
__global__ __launch_bounds__(256) void store_out_kernel(const float* __restrict__ X,
                                                        float* __restrict__ out, int n) {
    int i = blockIdx.x * 256 + threadIdx.x;
    if (i < n) out[i] = X[i];
}

extern "C" void kernel_launch(void* const* d_in, const int* in_sizes, int n_in,
                              void* d_out, int out_size, void* d_ws, size_t ws_size,
                              hipStream_t stream) {
    const int*   targets = (const int*)d_in[0];
    const int*   tlen    = (const int*)d_in[1];
    const float* enc     = (const float*)d_in[2];
    const int*   elen    = (const int*)d_in[3];
    const float* emb     = (const float*)d_in[4];
    const float* W_in    = (const float*)d_in[5];
    const float* b_in    = (const float*)d_in[6];
    const float* ln1_g   = (const float*)d_in[7];
    const float* ln1_b   = (const float*)d_in[8];
    const float* Wq1 = (const float*)d_in[9],  *bq1 = (const float*)d_in[10];
    const float* Wk1 = (const float*)d_in[11], *bk1 = (const float*)d_in[12];
    const float* Wv1 = (const float*)d_in[13], *bv1 = (const float*)d_in[14];
    const float* Wo1 = (const float*)d_in[15], *bo1 = (const float*)d_in[16];
    const float* ln2_g = (const float*)d_in[17], *ln2_b = (const float*)d_in[18];
    const float* Wq2 = (const float*)d_in[19], *bq2 = (const float*)d_in[20];
    const float* Wk2 = (const float*)d_in[21], *bk2 = (const float*)d_in[22];
    const float* Wv2 = (const float*)d_in[23], *bv2 = (const float*)d_in[24];
    const float* Wo2 = (const float*)d_in[25], *bo2 = (const float*)d_in[26];
    const float* ln3_g = (const float*)d_in[27], *ln3_b = (const float*)d_in[28];
    const float* W_ff1 = (const float*)d_in[29], *b_ff1 = (const float*)d_in[30];
    const float* W_ff2 = (const float*)d_in[31], *b_ff2 = (const float*)d_in[32];

    float* ws   = (float*)d_ws;
    float* x    = ws;                              // 4096x512 f32
    u16*   hb   = (u16*)(ws + 2097152);            // 4096x512 bf16
    u16*   qb   = (u16*)(ws + 3145728);            // 4096x512 bf16
    u16*   ctx  = (u16*)(ws + 4194304);            // 4096x512 bf16
    u16*   kb   = (u16*)(ws + 5242880);            // 16384x512 bf16
    u16*   vb   = (u16*)(ws + 9437184);            // 16384x512 bf16
    u16*   encb = (u16*)(ws + 13631488);           // 16384x512 bf16
    u16*   ffh  = kb;                              // 4096x2048 bf16 (aliases kb)

    const dim3 gdm(4, 32);     // M=4096,  N=512
    const dim3 gkv(4, 128);    // M=16384, N=512
    const dim3 gf1(16, 32);    // M=4096,  N=2048
    const dim3 gattn(TD / 64, NH, BB);

    cvt_kernel<<<8192, 256, 0, stream>>>(enc, encb, BB * TE * DM / 4);
    embed_kernel<<<4096, 256, 0, stream>>>(targets, emb, hb);
    gemm_mfma<false, false, false><<<gdm, 256, 0, stream>>>(hb, W_in, 0, b_in, 0, nullptr, x, 4096, 512, 512);

    for (int l = 0; l < NL; ++l) {
        const size_t wo = (size_t)l * DM * DM;
        const size_t fo = (size_t)l * DM * DFF;
        const size_t vo = (size_t)l * DM;
        const size_t fv = (size_t)l * DFF;

        ln_kernel<<<4096, 256, 0, stream>>>(x, ln1_g, ln1_b, vo, hb);
        gemm_mfma<true, false, false><<<gdm, 256, 0, stream>>>(hb, Wq1, wo, bq1, vo, nullptr, qb, 4096, 512, 512);
        gemm_mfma<true, false, false><<<gdm, 256, 0, stream>>>(hb, Wk1, wo, bk1, vo, nullptr, kb, 4096, 512, 512);
        gemm_mfma<true, false, false><<<gdm, 256, 0, stream>>>(hb, Wv1, wo, bv1, vo, nullptr, vb, 4096, 512, 512);
        fattn_mfma<<<gattn, 256, 0, stream>>>(qb, kb, vb, tlen, ctx, TD, TD, 1);
        gemm_mfma<false, false, true><<<gdm, 256, 0, stream>>>(ctx, Wo1, wo, bo1, vo, x, x, 4096, 512, 512);

        ln_kernel<<<4096, 256, 0, stream>>>(x, ln2_g, ln2_b, vo, hb);
        gemm_mfma<true, false, false><<<gdm, 256, 0, stream>>>(hb, Wq2, wo, bq2, vo, nullptr, qb, 4096, 512, 512);
        gemm_mfma<true, false, false><<<gkv, 256, 0, stream>>>(encb, Wk2, wo, bk2, vo, nullptr, kb, 16384, 512, 512);
        gemm_mfma<true, false, false><<<gkv, 256, 0, stream>>>(encb, Wv2, wo, bv2, vo, nullptr, vb, 16384, 512, 512);
        fattn_mfma<<<gattn, 256, 0, stream>>>(qb, kb, vb, elen, ctx, TD, TE, 0);
        gemm_mfma<false, false, true><<<gdm, 256, 0, stream>>>(ctx, Wo2, wo, bo2, vo, x, x, 4096, 512, 512);

        ln_kernel<<<4096, 256, 0, stream>>>(x, ln3_g, ln3_b, vo, hb);
        gemm_mfma<true, true, false><<<gf1, 256, 0, stream>>>(hb, W_ff1, fo, b_ff1, fv, nullptr, ffh, 4096, 2048, 512);
        gemm_mfma<false, false, true><<<gdm, 256, 0, stream>>>(ffh, W_ff2, fo, b_ff2, vo, x, x, 4096, 512, 2048);
    }

    store_out_kernel<<<8192, 256, 0, stream>>>(x, (float*)d_out, BB * TD * DM);
}

// Round 7
// 1706.238 us; speedup vs baseline: 11.2120x; 1.4496x over previous
//
#include <hip/hip_runtime.h>
#include <hip/hip_bf16.h>

#define BB   16
#define TD   256
#define TE   1024
#define DM   512
#define DFF  2048
#define NL   6
#define NH   8
#define DH   64

typedef unsigned short u16;
typedef short short8 __attribute__((ext_vector_type(8)));
typedef float f32x4 __attribute__((ext_vector_type(4)));

__device__ __forceinline__ float b2f(u16 u) {
    unsigned int x = ((unsigned int)u) << 16;
    float f;
    __builtin_memcpy(&f, &x, 4);
    return f;
}
__device__ __forceinline__ u16 f2b(float f) {           // round-to-nearest-even
    unsigned int x;
    __builtin_memcpy(&x, &f, 4);
    unsigned int r = x + 0x7fffu + ((x >> 16) & 1u);
    return (u16)(r >> 16);
}

// async global->LDS, 16B per lane, LDS dest = wave-uniform base + lane*16
__device__ __forceinline__ void gload_lds16(const u16* g, u16* l) {
    __builtin_amdgcn_global_load_lds(
        (const __attribute__((address_space(1))) unsigned int*)g,
        (__attribute__((address_space(3))) unsigned int*)l, 16, 0, 0);
}

// ---------------- f32 -> bf16 bulk convert (enc) ----------------
__global__ __launch_bounds__(256) void cvt_kernel(const float* __restrict__ in,
                                                  u16* __restrict__ out, int n4) {
    int i = blockIdx.x * 256 + threadIdx.x;
    if (i < n4) {
        float4 v = reinterpret_cast<const float4*>(in)[i];
        ushort4 o;
        o.x = f2b(v.x); o.y = f2b(v.y); o.z = f2b(v.z); o.w = f2b(v.w);
        reinterpret_cast<ushort4*>(out)[i] = o;
    }
}

// ---------------- weight transpose+convert: W[K][N] f32 -> Wt[N][K] bf16 -------
template <int NMAT>
struct PtrArr { const float* p[NMAT]; };

template <int NMAT>
__global__ __launch_bounds__(256) void tr_kernel(PtrArr<NMAT> P, u16* __restrict__ out,
                                                 int K, int N) {
    __shared__ u16 t[64][65];
    const float* W = P.p[blockIdx.z];
    u16* O = out + (size_t)blockIdx.z * K * N;
    int n0 = blockIdx.x * 64, k0 = blockIdx.y * 64;
    int tid = threadIdx.x;
    int r = tid >> 4, c = (tid & 15) * 4;
#pragma unroll
    for (int p = 0; p < 4; ++p) {
        int k = r + p * 16;
        float4 v = *reinterpret_cast<const float4*>(&W[(size_t)(k0 + k) * N + n0 + c]);
        t[c + 0][k] = f2b(v.x);
        t[c + 1][k] = f2b(v.y);
        t[c + 2][k] = f2b(v.z);
        t[c + 3][k] = f2b(v.w);
    }
    __syncthreads();
#pragma unroll
    for (int p = 0; p < 4; ++p) {
        int n = r + p * 16;
        ushort4 o;
        o.x = t[n][c]; o.y = t[n][c + 1]; o.z = t[n][c + 2]; o.w = t[n][c + 3];
        *reinterpret_cast<ushort4*>(&O[(size_t)(n0 + n) * K + k0 + c]) = o;
    }
}

// ---------------- embedding + sinusoidal PE -> bf16 ----------------
__global__ __launch_bounds__(256) void embed_kernel(const int* __restrict__ targets,
                                                    const float* __restrict__ emb,
                                                    u16* __restrict__ out) {
    int row = blockIdx.x;
    int t   = row & (TD - 1);
    int tgt = targets[row];
    const float c = -0.017988946039015984f;   // -ln(10000)/512
    for (int d = threadIdx.x; d < DM; d += 256) {
        float e   = emb[(size_t)tgt * DM + d] * 22.627416997969522f;  // sqrt(512)
        int   i2  = d & ~1;
        float div = expf(c * (float)i2);
        float arg = (float)t * div;
        float pe  = (d & 1) ? cosf(arg) : sinf(arg);
        out[(size_t)row * DM + d] = f2b(e + pe);
    }
}

// ---------------- layernorm: f32 in -> bf16 out ----------------
__global__ __launch_bounds__(256) void ln_kernel(const float* __restrict__ X,
                                                 const float* __restrict__ g,
                                                 const float* __restrict__ b,
                                                 size_t vo,
                                                 u16* __restrict__ O) {
    int row = blockIdx.x;
    const float* xr = X + (size_t)row * DM;
    int tid = threadIdx.x;
    float v0 = xr[tid], v1 = xr[tid + 256];
    float s = v0 + v1;
    __shared__ float red[4];
    int lane = tid & 63, wid = tid >> 6;
#pragma unroll
    for (int off = 32; off; off >>= 1) s += __shfl_xor(s, off);
    if (lane == 0) red[wid] = s;
    __syncthreads();
    float mean = (red[0] + red[1] + red[2] + red[3]) * (1.0f / 512.0f);
    float d0 = v0 - mean, d1 = v1 - mean;
    float sq = d0 * d0 + d1 * d1;
#pragma unroll
    for (int off = 32; off; off >>= 1) sq += __shfl_xor(sq, off);
    __syncthreads();
    if (lane == 0) red[wid] = sq;
    __syncthreads();
    float var = (red[0] + red[1] + red[2] + red[3]) * (1.0f / 512.0f);
    float rs  = rsqrtf(var + 1e-5f);
    O[(size_t)row * DM + tid]       = f2b(d0 * rs * g[vo + tid]       + b[vo + tid]);
    O[(size_t)row * DM + tid + 256] = f2b(d1 * rs * g[vo + tid + 256] + b[vo + tid + 256]);
}

// ---------------- m97-style GEMM: C = act(A[MxK] @ Wt[NxK]^T + bias) (+resid) ---
// BK=32. LDS tiles packed [row][k] u16, NO padding (global_load_lds lane order).
// 256 thr = 4 waves (2x2), per-wave tile (TM/2)x(TN/2) via 16x16x32 MFMA.
template <int TM, int TN, bool OUTBF, bool RELU, bool RES>
__global__ __launch_bounds__(256) void gemm_bt(const u16* __restrict__ A,
                                               const u16* __restrict__ Bt,
                                               const float* __restrict__ bias, size_t bofs,
                                               const float* __restrict__ resid,
                                               void* __restrict__ C,
                                               int M, int N, int K) {
    __shared__ u16 As[TM * 32];
    __shared__ u16 Bs[TN * 32];
    int tid = threadIdx.x, wave = tid >> 6, lane = tid & 63;
    int col0 = blockIdx.x * TN, row0 = blockIdx.y * TM;
    constexpr int WM = TM / 2, WN = TN / 2;
    int wm = (wave >> 1) * WM, wn = (wave & 1) * WN;
    int lq = lane >> 4, lc = lane & 15;
    constexpr int NI = WM / 16, NJ = WN / 16;
    f32x4 acc[NI][NJ] = {};
    int srow = lane >> 2;          // 0..15 row within 16-row staging group
    int scol = (lane & 3) * 8;     // k element offset (8 bf16 = 16 B)

    for (int k0 = 0; k0 < K; k0 += 32) {
#pragma unroll
        for (int s = 0; s < TM / 64; ++s) {
            int rbase = wave * (TM / 4) + s * 16;
            gload_lds16(A + (size_t)(row0 + rbase + srow) * K + k0 + scol, &As[rbase * 32]);
        }
#pragma unroll
        for (int s = 0; s < TN / 64; ++s) {
            int rbase = wave * (TN / 4) + s * 16;
            gload_lds16(Bt + (size_t)(col0 + rbase + srow) * K + k0 + scol, &Bs[rbase * 32]);
        }
        __syncthreads();

        short8 af[NI], bf[NJ];
#pragma unroll
        for (int i = 0; i < NI; ++i)
            af[i] = *reinterpret_cast<const short8*>(&As[(wm + i * 16 + lc) * 32 + lq * 8]);
#pragma unroll
        for (int j = 0; j < NJ; ++j)
            bf[j] = *reinterpret_cast<const short8*>(&Bs[(wn + j * 16 + lc) * 32 + lq * 8]);
#pragma unroll
        for (int i = 0; i < NI; ++i)
#pragma unroll
            for (int j = 0; j < NJ; ++j)
                acc[i][j] = __builtin_amdgcn_mfma_f32_16x16x32_bf16(af[i], bf[j], acc[i][j], 0, 0, 0);
        __syncthreads();
    }

    // epilogue: C/D layout col=lane&15, row=quad*4+reg
#pragma unroll
    for (int j = 0; j < NJ; ++j) {
        int n = col0 + wn + j * 16 + lc;
        float bv = bias[bofs + n];
#pragma unroll
        for (int i = 0; i < NI; ++i) {
#pragma unroll
            for (int r = 0; r < 4; ++r) {
                int m = row0 + wm + i * 16 + lq * 4 + r;
                float v = acc[i][j][r] + bv;
                if (RES)  v += resid[(size_t)m * N + n];
                if (RELU) v = fmaxf(v, 0.0f);
                if (OUTBF) ((u16*)C)[(size_t)m * N + n] = f2b(v);
                else       ((float*)C)[(size_t)m * N + n] = v;
            }
        }
    }
}

// ---------------- MFMA flash attention (unchanged from round 6) ----------------
#define QSTR 72
#define VSTR 66

__global__ __launch_bounds__(256) void fattn_mfma(const u16* __restrict__ Q,
                                                  const u16* __restrict__ K,
                                                  const u16* __restrict__ V,
                                                  const int* __restrict__ lens,
                                                  u16* __restrict__ O,
                                                  int Tq, int Tk, int causal) {
    __shared__ u16 Qs[64 * QSTR];
    __shared__ u16 Ks[64 * QSTR];
    __shared__ u16 Ps[64 * QSTR];
    __shared__ u16 Vs[64 * VSTR];
    int tid  = threadIdx.x;
    int qt0  = blockIdx.x * 64;
    int h    = blockIdx.y;
    int b    = blockIdx.z;
    int len  = lens[b];
    int wave = tid >> 6, lane = tid & 63;
    int lq = lane >> 4, lc = lane & 15;
    int sr = tid >> 4;
    int sd = (tid & 15) * 4;

#pragma unroll
    for (int i = 0; i < 4; ++i) {
        int q = sr + i * 16;
        ushort4 v = *reinterpret_cast<const ushort4*>(
            &Q[(size_t)(b * Tq + qt0 + q) * DM + h * DH + sd]);
        ushort4 w;
        w.x = f2b(b2f(v.x) * 0.125f); w.y = f2b(b2f(v.y) * 0.125f);
        w.z = f2b(b2f(v.z) * 0.125f); w.w = f2b(b2f(v.w) * 0.125f);
        *reinterpret_cast<ushort4*>(&Qs[q * QSTR + sd]) = w;
    }
    __syncthreads();

    short8 aq0 = *reinterpret_cast<const short8*>(&Qs[(wave * 16 + lc) * QSTR + lq * 8]);
    short8 aq1 = *reinterpret_cast<const short8*>(&Qs[(wave * 16 + lc) * QSTR + 32 + lq * 8]);

    f32x4 Ow[4] = {};
    float m[4], l[4];
#pragma unroll
    for (int r = 0; r < 4; ++r) { m[r] = -1e30f; l[r] = 0.0f; }

    int kend = causal ? min(len, qt0 + 64) : len;
    for (int kt0 = 0; kt0 < kend; kt0 += 64) {
        __syncthreads();
#pragma unroll
        for (int i = 0; i < 4; ++i) {
            int k = sr + i * 16;
            ushort4 kv = *reinterpret_cast<const ushort4*>(
                &K[(size_t)(b * Tk + kt0 + k) * DM + h * DH + sd]);
            *reinterpret_cast<ushort4*>(&Ks[k * QSTR + sd]) = kv;
            ushort4 vv = *reinterpret_cast<const ushort4*>(
                &V[(size_t)(b * Tk + kt0 + k) * DM + h * DH + sd]);
            Vs[(sd + 0) * VSTR + k] = vv.x;
            Vs[(sd + 1) * VSTR + k] = vv.y;
            Vs[(sd + 2) * VSTR + k] = vv.z;
            Vs[(sd + 3) * VSTR + k] = vv.w;
        }
        __syncthreads();

        f32x4 sa[4] = {};
#pragma unroll
        for (int n = 0; n < 4; ++n) {
            short8 bk0 = *reinterpret_cast<const short8*>(&Ks[(n * 16 + lc) * QSTR + lq * 8]);
            short8 bk1 = *reinterpret_cast<const short8*>(&Ks[(n * 16 + lc) * QSTR + 32 + lq * 8]);
            sa[n] = __builtin_amdgcn_mfma_f32_16x16x32_bf16(aq0, bk0, sa[n], 0, 0, 0);
            sa[n] = __builtin_amdgcn_mfma_f32_16x16x32_bf16(aq1, bk1, sa[n], 0, 0, 0);
        }

        int qrow_base = qt0 + wave * 16 + lq * 4;
#pragma unroll
        for (int r = 0; r < 4; ++r) {
            int qrow = qrow_base + r;
            float sv[4];
#pragma unroll
            for (int n = 0; n < 4; ++n) {
                int key = kt0 + n * 16 + lc;
                bool inv = (key >= len) || (causal && key > qrow);
                sv[n] = inv ? -1e30f : sa[n][r];
            }
            float rm = fmaxf(fmaxf(sv[0], sv[1]), fmaxf(sv[2], sv[3]));
#pragma unroll
            for (int off = 1; off < 16; off <<= 1) rm = fmaxf(rm, __shfl_xor(rm, off));
            float mn = fmaxf(m[r], rm);
            float alpha = __expf(m[r] - mn);
            m[r] = mn;
            float rs = 0.0f;
#pragma unroll
            for (int n = 0; n < 4; ++n) {
                float p = __expf(sv[n] - mn);
                rs += p;
                Ps[(wave * 16 + lq * 4 + r) * QSTR + n * 16 + lc] = f2b(p);
            }
#pragma unroll
            for (int off = 1; off < 16; off <<= 1) rs += __shfl_xor(rs, off);
            l[r] = l[r] * alpha + rs;
#pragma unroll
            for (int n = 0; n < 4; ++n) Ow[n][r] *= alpha;
        }
        __syncthreads();

        short8 ap0 = *reinterpret_cast<const short8*>(&Ps[(wave * 16 + lc) * QSTR + lq * 8]);
        short8 ap1 = *reinterpret_cast<const short8*>(&Ps[(wave * 16 + lc) * QSTR + 32 + lq * 8]);
#pragma unroll
        for (int n = 0; n < 4; ++n) {
#pragma unroll
            for (int ks = 0; ks < 2; ++ks) {
                int base = (n * 16 + lc) * VSTR + ks * 32 + lq * 8;
                const int* vp = reinterpret_cast<const int*>(&Vs[base]);
                int w[4] = { vp[0], vp[1], vp[2], vp[3] };
                short8 bv;
                __builtin_memcpy(&bv, w, 16);
                Ow[n] = __builtin_amdgcn_mfma_f32_16x16x32_bf16(ks ? ap1 : ap0, bv, Ow[n], 0, 0, 0);
            }
        }
    }

#pragma unroll
    for (int r = 0; r < 4; ++r) {
        float inv = 1.0f / l[r];
        size_t rowoff = (size_t)(b * Tq + qt0 + wave * 16 + lq * 4 + r) * DM + h * DH;
#pragma unroll
        for (int n = 0; n < 4; ++n)
            O[rowoff + n * 16 + lc] = f2b(Ow[n][r] * inv);
    }
}

// ---------------- f32 -> f32 output ----------------
__global__ __launch_bounds__(256) void store_out_kernel(const float* __restrict__ X,
                                                        float* __restrict__ out, int n) {
    int i = blockIdx.x * 256 + threadIdx.x;
    if (i < n) out[i] = X[i];
}

extern "C" void kernel_launch(void* const* d_in, const int* in_sizes, int n_in,
                              void* d_out, int out_size, void* d_ws, size_t ws_size,
                              hipStream_t stream) {
    const int*   targets = (const int*)d_in[0];
    const int*   tlen    = (const int*)d_in[1];
    const float* enc     = (const float*)d_in[2];
    const int*   elen    = (const int*)d_in[3];
    const float* emb     = (const float*)d_in[4];
    const float* W_in    = (const float*)d_in[5];
    const float* b_in    = (const float*)d_in[6];
    const float* ln1_g   = (const float*)d_in[7];
    const float* ln1_b   = (const float*)d_in[8];
    const float* Wq1 = (const float*)d_in[9],  *bq1 = (const float*)d_in[10];
    const float* Wk1 = (const float*)d_in[11], *bk1 = (const float*)d_in[12];
    const float* Wv1 = (const float*)d_in[13], *bv1 = (const float*)d_in[14];
    const float* Wo1 = (const float*)d_in[15], *bo1 = (const float*)d_in[16];
    const float* ln2_g = (const float*)d_in[17], *ln2_b = (const float*)d_in[18];
    const float* Wq2 = (const float*)d_in[19], *bq2 = (const float*)d_in[20];
    const float* Wk2 = (const float*)d_in[21], *bk2 = (const float*)d_in[22];
    const float* Wv2 = (const float*)d_in[23], *bv2 = (const float*)d_in[24];
    const float* Wo2 = (const float*)d_in[25], *bo2 = (const float*)d_in[26];
    const float* ln3_g = (const float*)d_in[27], *ln3_b = (const float*)d_in[28];
    const float* W_ff1 = (const float*)d_in[29], *b_ff1 = (const float*)d_in[30];
    const float* W_ff2 = (const float*)d_in[31], *b_ff2 = (const float*)d_in[32];

    float* ws   = (float*)d_ws;
    float* x    = ws;                              // 4096x512 f32
    u16*   hb   = (u16*)(ws + 2097152);            // 4096x512 bf16
    u16*   qb   = (u16*)(ws + 3145728);            // 4096x512 bf16
    u16*   ctx  = (u16*)(ws + 4194304);            // 4096x512 bf16
    u16*   kb   = (u16*)(ws + 5242880);            // 16384x512 bf16
    u16*   vb   = (u16*)(ws + 9437184);            // 16384x512 bf16
    u16*   encb = (u16*)(ws + 13631488);           // 16384x512 bf16
    u16*   wt_dm = (u16*)(ws + 17825792);          // 49 x 512x512 bf16 [N][K]
    u16*   wt_f1 = (u16*)(ws + 24248320);          // 6 x 2048x512 bf16 [N][K]
    u16*   wt_f2 = (u16*)(ws + 27394048);          // 6 x 512x2048 bf16 [N][K]
    u16*   ffh  = kb;                              // 4096x2048 bf16 (aliases kb)

    // ---- weight transpose+convert (once per launch) ----
    PtrArr<49> pdm;
    pdm.p[0] = W_in;
    const float* dmw[8];
    for (int l = 0; l < NL; ++l) {
        const float* ws8[8] = { Wq1, Wk1, Wv1, Wo1, Wq2, Wk2, Wv2, Wo2 };
        for (int j = 0; j < 8; ++j) pdm.p[1 + l * 8 + j] = ws8[j] + (size_t)l * DM * DM;
    }
    (void)dmw;
    PtrArr<6> pf1, pf2;
    for (int l = 0; l < NL; ++l) {
        pf1.p[l] = W_ff1 + (size_t)l * DM * DFF;
        pf2.p[l] = W_ff2 + (size_t)l * DFF * DM;
    }
    tr_kernel<49><<<dim3(8, 8, 49), 256, 0, stream>>>(pdm, wt_dm, 512, 512);
    tr_kernel<6><<<dim3(32, 8, 6), 256, 0, stream>>>(pf1, wt_f1, 512, 2048);
    tr_kernel<6><<<dim3(8, 32, 6), 256, 0, stream>>>(pf2, wt_f2, 2048, 512);

    const size_t WDM = (size_t)512 * 512;
    const size_t WFF = (size_t)512 * 2048;

    const dim3 gdm(8, 64);      // 64x64 tiles: M=4096,  N=512  -> 512 blocks
    const dim3 gkv(4, 128);     // 128x128:    M=16384, N=512  -> 512 blocks
    const dim3 gf1(16, 32);     // 128x128:    M=4096,  N=2048 -> 512 blocks
    const dim3 gattn(TD / 64, NH, BB);

    cvt_kernel<<<8192, 256, 0, stream>>>(enc, encb, BB * TE * DM / 4);
    embed_kernel<<<4096, 256, 0, stream>>>(targets, emb, hb);
    gemm_bt<64, 64, false, false, false><<<gdm, 256, 0, stream>>>(hb, wt_dm, b_in, 0, nullptr, x, 4096, 512, 512);

    for (int l = 0; l < NL; ++l) {
        const size_t vo = (size_t)l * DM;
        const size_t fv = (size_t)l * DFF;
        const u16* tq1 = wt_dm + (1 + l * 8 + 0) * WDM;
        const u16* tk1 = wt_dm + (1 + l * 8 + 1) * WDM;
        const u16* tv1 = wt_dm + (1 + l * 8 + 2) * WDM;
        const u16* to1 = wt_dm + (1 + l * 8 + 3) * WDM;
        const u16* tq2 = wt_dm + (1 + l * 8 + 4) * WDM;
        const u16* tk2 = wt_dm + (1 + l * 8 + 5) * WDM;
        const u16* tv2 = wt_dm + (1 + l * 8 + 6) * WDM;
        const u16* to2 = wt_dm + (1 + l * 8 + 7) * WDM;
        const u16* tf1 = wt_f1 + l * WFF;
        const u16* tf2 = wt_f2 + l * WFF;

        ln_kernel<<<4096, 256, 0, stream>>>(x, ln1_g, ln1_b, vo, hb);
        gemm_bt<64, 64, true, false, false><<<gdm, 256, 0, stream>>>(hb, tq1, bq1, vo, nullptr, qb, 4096, 512, 512);
        gemm_bt<64, 64, true, false, false><<<gdm, 256, 0, stream>>>(hb, tk1, bk1, vo, nullptr, kb, 4096, 512, 512);
        gemm_bt<64, 64, true, false, false><<<gdm, 256, 0, stream>>>(hb, tv1, bv1, vo, nullptr, vb, 4096, 512, 512);
        fattn_mfma<<<gattn, 256, 0, stream>>>(qb, kb, vb, tlen, ctx, TD, TD, 1);
        gemm_bt<64, 64, false, false, true><<<gdm, 256, 0, stream>>>(ctx, to1, bo1, vo, x, x, 4096, 512, 512);

        ln_kernel<<<4096, 256, 0, stream>>>(x, ln2_g, ln2_b, vo, hb);
        gemm_bt<64, 64, true, false, false><<<gdm, 256, 0, stream>>>(hb, tq2, bq2, vo, nullptr, qb, 4096, 512, 512);
        gemm_bt<128, 128, true, false, false><<<gkv, 256, 0, stream>>>(encb, tk2, bk2, vo, nullptr, kb, 16384, 512, 512);
        gemm_bt<128, 128, true, false, false><<<gkv, 256, 0, stream>>>(encb, tv2, bv2, vo, nullptr, vb, 16384, 512, 512);
        fattn_mfma<<<gattn, 256, 0, stream>>>(qb, kb, vb, elen, ctx, TD, TE, 0);
        gemm_bt<64, 64, false, false, true><<<gdm, 256, 0, stream>>>(ctx, to2, bo2, vo, x, x, 4096, 512, 512);

        ln_kernel<<<4096, 256, 0, stream>>>(x, ln3_g, ln3_b, vo, hb);
        gemm_bt<128, 128, true, true, false><<<gf1, 256, 0, stream>>>(hb, tf1, b_ff1, fv, nullptr, ffh, 4096, 2048, 512);
        gemm_bt<64, 64, false, false, true><<<gdm, 256, 0, stream>>>(ffh, tf2, b_ff2, vo, x, x, 4096, 512, 2048);
    }

    store_out_kernel<<<8192, 256, 0, stream>>>(x, (float*)d_out, BB * TD * DM);
}